// Round 10
// baseline (727.038 us; speedup 1.0000x reference)
//
#include <hip/hip_runtime.h>
#include <hip/hip_bf16.h>
#include <cstdint>

#define B_  64
#define T_  32
#define E_  300
#define EP  320      // padded K for the x-precompute GEMM
#define H_  1024
#define G4  4096     // 4*H
#define BH  65536    // B_*H_
#define NBLK 192     // persistent blocks: 64 L1 + 64 I2 + 64 H2

typedef __attribute__((ext_vector_type(8))) short bf16x8;
typedef __attribute__((ext_vector_type(4))) float f32x4;
typedef unsigned short ushort_t;

__device__ __forceinline__ bf16x8 load_b8(const ushort_t* p) {
    union { uint4 u; bf16x8 v; } c;
    c.u = *reinterpret_cast<const uint4*>(p);
    return c.v;
}

__device__ __forceinline__ ushort_t f2bf(float x) {
    union { float f; uint32_t u; } c; c.f = x;
    uint32_t r = c.u + 0x7fffu + ((c.u >> 16) & 1u);   // RNE
    return (ushort_t)(r >> 16);
}

__device__ __forceinline__ float sigm(float x) { return 1.0f / (1.0f + __expf(-x)); }

// agent-scope (cross-XCD write-through) stores for produced data; plain loads
// on the consumer side (unique buffer per timestep => no stale lines)
__device__ __forceinline__ void astore64(uint64_t* p, uint64_t v) {
    __hip_atomic_store(p, v, __ATOMIC_RELAXED, __HIP_MEMORY_SCOPE_AGENT);
}
__device__ __forceinline__ uint64_t packf2(float a, float b) {
    union { float f[2]; uint64_t u; } c; c.f[0] = a; c.f[1] = b; return c.u;
}

// ---- contention-free dataflow flags ----
__device__ __forceinline__ void setflag(int* flags, int role, int js, int val) {
    __hip_atomic_store(&flags[(role * 64 + js) * 16], val,
                       __ATOMIC_RELAXED, __HIP_MEMORY_SCOPE_AGENT);
}
__device__ __forceinline__ void waitwave(const int* flags, int role, int target, int lane) {
    const int* p = &flags[(role * 64 + lane) * 16];
    int guard = 0;
    for (;;) {
        int v = __hip_atomic_load(p, __ATOMIC_RELAXED, __HIP_MEMORY_SCOPE_AGENT);
        if (__all(v >= target)) return;
        if (++guard > (1 << 22)) return;        // diagnostic bail-out (never hit when healthy)
        __builtin_amdgcn_s_sleep(1);
    }
}

// ---------------- fused prep kernel ----------------
// [0,1280): embed gather+pad ; [1280,3328): W_ih1 pad+convert ;
// [3328,3392): zero h1hist/h2hist slot 0 ; [3392,3395): zero flags
__global__ void prep_inputs(const int* __restrict__ q, const float* __restrict__ table,
                            ushort_t* __restrict__ Xp,
                            const float* __restrict__ Wsrc, ushort_t* __restrict__ Wdst,
                            ushort_t* __restrict__ h1s0, ushort_t* __restrict__ h2s0,
                            int* __restrict__ flags) {
    int blk = blockIdx.x;
    if (blk < 1280) {
        int i = blk * 256 + threadIdx.x;
        const int n = B_ * T_ * EP;
        for (; i < n; i += 1280 * 256) {
            int r = i / EP, c = i - r * EP;
            Xp[i] = (c < E_) ? f2bf(table[q[r] * E_ + c]) : (ushort_t)0;
        }
    } else if (blk < 3328) {
        int i = (blk - 1280) * 256 + threadIdx.x;
        const int n = G4 * EP;
        for (; i < n; i += 2048 * 256) {
            int r = i / EP, c = i - r * EP;
            Wdst[i] = (c < E_) ? f2bf(Wsrc[r * E_ + c]) : (ushort_t)0;
        }
    } else if (blk < 3392) {
        int i = (blk - 3328) * 256 + threadIdx.x;       // 0..16383 uint4
        uint4 z = make_uint4(0, 0, 0, 0);
        if (i < 8192) reinterpret_cast<uint4*>(h1s0)[i] = z;
        else          reinterpret_cast<uint4*>(h2s0)[i - 8192] = z;
    } else {
        int i = (blk - 3392) * 256 + threadIdx.x;       // 0..767 uint4 = 12,288 B
        reinterpret_cast<uint4*>(flags)[i] = make_uint4(0, 0, 0, 0);
    }
}

// ---------------- x-part precompute GEMM ----------------
// xg[t][b][j][4gates] fp32 (gate-interleaved) -> role-0 reads ONE uint4/(b,j)
__launch_bounds__(256)
__global__ void xgemm(const ushort_t* __restrict__ Xp, const ushort_t* __restrict__ Wp,
                      const float* __restrict__ b_ih1, const float* __restrict__ b_hh1,
                      float* __restrict__ xg) {
    int mblk = blockIdx.x, nblk = blockIdx.y;
    int wave = threadIdx.x >> 6, lane = threadIdx.x & 63;
    int lm = lane & 15, lq = lane >> 4;
    int m0 = mblk * 64 + wave * 16;
    f32x4 acc[4];
    #pragma unroll
    for (int g = 0; g < 4; ++g) {
        int n = nblk * 64 + g * 16 + lm;
        float bv = b_ih1[n] + b_hh1[n];
        acc[g] = (f32x4){bv, bv, bv, bv};
    }
    for (int k0 = 0; k0 < EP; k0 += 32) {
        bf16x8 a = load_b8(Xp + (m0 + lm) * EP + k0 + lq * 8);
        #pragma unroll
        for (int g = 0; g < 4; ++g) {
            bf16x8 b = load_b8(Wp + (nblk * 64 + g * 16 + lm) * EP + k0 + lq * 8);
            acc[g] = __builtin_amdgcn_mfma_f32_16x16x32_bf16(a, b, acc[g], 0, 0, 0);
        }
    }
    #pragma unroll
    for (int g = 0; g < 4; ++g)
        #pragma unroll
        for (int r = 0; r < 4; ++r) {
            int m = m0 + lq * 4 + r;          // m = b*T + t
            int b = m >> 5, t = m & 31;
            int n = nblk * 64 + g * 16 + lm;  // raw 4H index
            int gate = n >> 10, j = n & 1023;
            xg[(((size_t)t * B_ + b) * H_ + j) * 4 + gate] = acc[g][r];
        }
}

// ---------------- persistent recurrence kernel ----------------
// 8 waves/block (512 thr). wave w: kq = w&3 (K-quarter 256), mh = w>>2 (m-half 32).
// WEIGHTS LIVE IN VGPRs: each wave holds its N=64 x K=256 weight slice as 32
// bf16x8 fragments (128 VGPRs), loaded once -> zero per-step LDS B-traffic.
// K-reduction: kq!=0 dump acc to pacc (conflict-free layout), kq==0 sums,
// applies gates (all 4 gates resident per wave), stores h tile.

__device__ __forceinline__ void gemm_q(const uint4* __restrict__ hr,
                                       const bf16x8 (&wfr)[32],
                                       int rbase, int cbase, f32x4 acc[2][4]) {
    #pragma unroll
    for (int half = 0; half < 2; ++half) {
        uint4 af[8];
        #pragma unroll
        for (int i = 0; i < 8; ++i) {
            int kc = half * 4 + (i >> 1), mi = i & 1;
            af[i] = hr[cbase + kc * 256 + rbase + mi * 32];
        }
        #pragma unroll
        for (int k4 = 0; k4 < 4; ++k4) {
            int kc = half * 4 + k4;
            #pragma unroll
            for (int mi = 0; mi < 2; ++mi) {
                union { uint4 u; bf16x8 v; } a; a.u = af[k4 * 2 + mi];
                #pragma unroll
                for (int nt = 0; nt < 4; ++nt)
                    acc[mi][nt] = __builtin_amdgcn_mfma_f32_16x16x32_bf16(
                        a.v, wfr[nt * 8 + kc], acc[mi][nt], 0, 0, 0);
            }
        }
    }
}

// col-major h-tile store: ONE contiguous 2KB burst per block (threads 0..255)
__device__ __forceinline__ void store_h_tile(ushort_t* slot, int js, const ushort_t* hst) {
    int tid = threadIdx.x;                     // caller guards tid < 256
    uint64_t v = reinterpret_cast<const uint64_t*>(hst)[tid];
    astore64(reinterpret_cast<uint64_t*>(slot) + js * 256 + tid, v);
}

__global__ __launch_bounds__(512, 2) void lstm_persist(
    const float* __restrict__ Whh1, const float* __restrict__ Wih2,
    const float* __restrict__ Whh2,
    const float* __restrict__ b_ih2, const float* __restrict__ b_hh2,
    const float* __restrict__ xg, const int* __restrict__ qlen,
    ushort_t* __restrict__ h1hist,   // 33 slots of BH bf16, col-major; slot k = h1(k-1)
    ushort_t* __restrict__ h2hist,   // 33 slots of BH bf16, col-major; slot k = h2(k-1)
    float* __restrict__ Qhist,       // 32 slots of BH*4 fp32, gate-interleaved [b][j][4]
    float* __restrict__ h1f, float* __restrict__ c1f,
    float* __restrict__ h2f, float* __restrict__ c2f,
    int* __restrict__ flags)
{
    __shared__ f32x4 pacc[8][6][64];               // 49,152 B, conflict-free
    __shared__ __align__(16) ushort_t hstage[64][16];  // 2,048 B

    const int blk  = blockIdx.x;
    const int role = blk >> 6;          // 0=L1, 1=I2, 2=H2
    const int js   = blk & 63;
    const int w    = threadIdx.x >> 6, lane = threadIdx.x & 63;
    const int kq   = w & 3, mh = w >> 2;
    const int lm = lane & 15, lq = lane >> 4;

    // ---- load weight fragments fp32 -> bf16 into VGPRs (once) ----
    const float* Wsrc = (role == 0) ? Whh1 : (role == 1) ? Wih2 : Whh2;
    bf16x8 wfr[32];
    #pragma unroll
    for (int nt = 0; nt < 4; ++nt)
        #pragma unroll
        for (int kc = 0; kc < 8; ++kc) {
            const float* p = Wsrc + (size_t)(nt * H_ + js * 16 + lm) * H_
                           + kq * 256 + kc * 32 + lq * 8;
            float4 v0 = *reinterpret_cast<const float4*>(p);
            float4 v1 = *reinterpret_cast<const float4*>(p + 4);
            union { uint32_t u[4]; bf16x8 v; } c;
            c.u[0] = (uint32_t)f2bf(v0.x) | ((uint32_t)f2bf(v0.y) << 16);
            c.u[1] = (uint32_t)f2bf(v0.z) | ((uint32_t)f2bf(v0.w) << 16);
            c.u[2] = (uint32_t)f2bf(v1.x) | ((uint32_t)f2bf(v1.y) << 16);
            c.u[3] = (uint32_t)f2bf(v1.z) | ((uint32_t)f2bf(v1.w) << 16);
            wfr[nt * 8 + kc] = c.v;
        }

    // A-fragment addressing into col-major h slot ([j-chunk16][b][16] ushorts):
    // uint4 idx = chunk*128 + row*2 + (lq&1), chunk = kq*16 + kc*2 + (lq>>1)
    const int rbase = (mh * 32 + lm) * 2 + (lq & 1);
    const int cbase = (kq * 16 + (lq >> 1)) * 128;

    int q[2][4];
    #pragma unroll
    for (int mi = 0; mi < 2; ++mi)
        #pragma unroll
        for (int r = 0; r < 4; ++r)
            q[mi][r] = qlen[mh * 32 + mi * 16 + lq * 4 + r];

    float    c_reg[2][4] = {};
    float    h_reg[2][4] = {};
    ushort_t hb_reg[2][4] = {};

    if (role == 0) {
        for (int t = 0; t < T_; ++t) {
            if (t > 0) {
                if (w == 0) waitwave(flags, 0, t, lane);   // h1 slot t complete
                __syncthreads();
            }
            f32x4 acc[2][4] = {};
            gemm_q(reinterpret_cast<const uint4*>(h1hist + (size_t)t * BH),
                   wfr, rbase, cbase, acc);
            uint4 xq[8];
            if (kq == 0) {                      // xg loads overlap dump+sync
                #pragma unroll
                for (int mi = 0; mi < 2; ++mi)
                    #pragma unroll
                    for (int r = 0; r < 4; ++r)
                        xq[mi * 4 + r] = reinterpret_cast<const uint4*>(xg)
                            [((size_t)t * B_ + (mh * 32 + mi * 16 + lq * 4 + r)) * H_ + js * 16 + lm];
            } else {
                #pragma unroll
                for (int mi = 0; mi < 2; ++mi)
                    #pragma unroll
                    for (int nt = 0; nt < 4; ++nt)
                        pacc[mi * 4 + nt][mh * 3 + (kq - 1)][lane] = acc[mi][nt];
            }
            __syncthreads();
            if (kq == 0) {
                #pragma unroll
                for (int s = 0; s < 3; ++s)
                    #pragma unroll
                    for (int mi = 0; mi < 2; ++mi)
                        #pragma unroll
                        for (int nt = 0; nt < 4; ++nt)
                            acc[mi][nt] += pacc[mi * 4 + nt][mh * 3 + s][lane];
                #pragma unroll
                for (int mi = 0; mi < 2; ++mi)
                    #pragma unroll
                    for (int r = 0; r < 4; ++r) {
                        union { uint32_t u; float f; } x0, x1, x2, x3;
                        x0.u = xq[mi * 4 + r].x; x1.u = xq[mi * 4 + r].y;
                        x2.u = xq[mi * 4 + r].z; x3.u = xq[mi * 4 + r].w;
                        float a0 = acc[0][0][0]; // placeholder avoided; real below
                        (void)a0;
                        float g0 = acc[mi][0][r] + x0.f;
                        float g1 = acc[mi][1][r] + x1.f;
                        float g2 = acc[mi][2][r] + x2.f;
                        float g3 = acc[mi][3][r] + x3.f;
                        if (t < q[mi][r]) {
                            float iv = sigm(g0), fv = sigm(g1);
                            float gv = tanhf(g2), ov = sigm(g3);
                            float cn = fv * c_reg[mi][r] + iv * gv;
                            float hv = ov * tanhf(cn);
                            c_reg[mi][r] = cn; h_reg[mi][r] = hv; hb_reg[mi][r] = f2bf(hv);
                        }
                        hstage[mh * 32 + mi * 16 + lq * 4 + r][lm] = hb_reg[mi][r];
                    }
            }
            __syncthreads();
            if (threadIdx.x < 256)
                store_h_tile(h1hist + (size_t)(t + 1) * BH, js, &hstage[0][0]);
            __syncthreads();                    // drain: stores visible
            if (threadIdx.x == 0) setflag(flags, 0, js, t + 1);
        }
        if (kq == 0) {
            #pragma unroll
            for (int mi = 0; mi < 2; ++mi)
                #pragma unroll
                for (int r = 0; r < 4; ++r) {
                    int b = mh * 32 + mi * 16 + lq * 4 + r, j = js * 16 + lm;
                    h1f[b * H_ + j] = h_reg[mi][r]; c1f[b * H_ + j] = c_reg[mi][r];
                }
        }
    } else if (role == 1) {
        float bi[4];
        #pragma unroll
        for (int g = 0; g < 4; ++g) {
            int n = g * H_ + js * 16 + lm;
            bi[g] = b_ih2[n] + b_hh2[n];
        }
        for (int t = 0; t < T_; ++t) {
            if (w == 0) waitwave(flags, 0, t + 1, lane);   // h1 slot t+1 complete
            __syncthreads();
            f32x4 acc[2][4] = {};
            gemm_q(reinterpret_cast<const uint4*>(h1hist + (size_t)(t + 1) * BH),
                   wfr, rbase, cbase, acc);
            if (kq != 0) {
                #pragma unroll
                for (int mi = 0; mi < 2; ++mi)
                    #pragma unroll
                    for (int nt = 0; nt < 4; ++nt)
                        pacc[mi * 4 + nt][mh * 3 + (kq - 1)][lane] = acc[mi][nt];
            }
            __syncthreads();
            if (kq == 0) {
                #pragma unroll
                for (int s = 0; s < 3; ++s)
                    #pragma unroll
                    for (int mi = 0; mi < 2; ++mi)
                        #pragma unroll
                        for (int nt = 0; nt < 4; ++nt)
                            acc[mi][nt] += pacc[mi * 4 + nt][mh * 3 + s][lane];
                uint64_t* Qw64 = (uint64_t*)(Qhist + (size_t)t * (4 * BH));
                #pragma unroll
                for (int mi = 0; mi < 2; ++mi)
                    #pragma unroll
                    for (int r = 0; r < 4; ++r) {
                        int b = mh * 32 + mi * 16 + lq * 4 + r, j = js * 16 + lm;
                        size_t base = ((size_t)b * H_ + j) * 2;
                        astore64(Qw64 + base,
                                 packf2(acc[mi][0][r] + bi[0], acc[mi][1][r] + bi[1]));
                        astore64(Qw64 + base + 1,
                                 packf2(acc[mi][2][r] + bi[2], acc[mi][3][r] + bi[3]));
                    }
            }
            __syncthreads();                    // drain
            if (threadIdx.x == 0) setflag(flags, 1, js, t + 1);
        }
    } else {
        for (int t = 0; t < T_; ++t) {
            if (w == 0)               waitwave(flags, 1, t + 1, lane); // Q slot t done
            else if (w == 1 && t > 0) waitwave(flags, 2, t,     lane); // h2 slot t done
            __syncthreads();
            f32x4 acc[2][4] = {};
            gemm_q(reinterpret_cast<const uint4*>(h2hist + (size_t)t * BH),
                   wfr, rbase, cbase, acc);
            uint4 qp[8];
            if (kq == 0) {                      // Q loads overlap dump+sync
                const uint4* Qr = (const uint4*)(Qhist + (size_t)t * (4 * BH));
                #pragma unroll
                for (int mi = 0; mi < 2; ++mi)
                    #pragma unroll
                    for (int r = 0; r < 4; ++r)
                        qp[mi * 4 + r] = Qr[(size_t)(mh * 32 + mi * 16 + lq * 4 + r) * H_ + js * 16 + lm];
            } else {
                #pragma unroll
                for (int mi = 0; mi < 2; ++mi)
                    #pragma unroll
                    for (int nt = 0; nt < 4; ++nt)
                        pacc[mi * 4 + nt][mh * 3 + (kq - 1)][lane] = acc[mi][nt];
            }
            __syncthreads();
            if (kq == 0) {
                #pragma unroll
                for (int s = 0; s < 3; ++s)
                    #pragma unroll
                    for (int mi = 0; mi < 2; ++mi)
                        #pragma unroll
                        for (int nt = 0; nt < 4; ++nt)
                            acc[mi][nt] += pacc[mi * 4 + nt][mh * 3 + s][lane];
                #pragma unroll
                for (int mi = 0; mi < 2; ++mi)
                    #pragma unroll
                    for (int r = 0; r < 4; ++r) {
                        union { uint32_t u; float f; } x0, x1, x2, x3;
                        x0.u = qp[mi * 4 + r].x; x1.u = qp[mi * 4 + r].y;
                        x2.u = qp[mi * 4 + r].z; x3.u = qp[mi * 4 + r].w;
                        float g0 = acc[mi][0][r] + x0.f;
                        float g1 = acc[mi][1][r] + x1.f;
                        float g2 = acc[mi][2][r] + x2.f;
                        float g3 = acc[mi][3][r] + x3.f;
                        if (t < q[mi][r]) {
                            float iv = sigm(g0), fv = sigm(g1);
                            float gv = tanhf(g2), ov = sigm(g3);
                            float cn = fv * c_reg[mi][r] + iv * gv;
                            float hv = ov * tanhf(cn);
                            c_reg[mi][r] = cn; h_reg[mi][r] = hv; hb_reg[mi][r] = f2bf(hv);
                        }
                        hstage[mh * 32 + mi * 16 + lq * 4 + r][lm] = hb_reg[mi][r];
                    }
            }
            __syncthreads();
            if (threadIdx.x < 256)
                store_h_tile(h2hist + (size_t)(t + 1) * BH, js, &hstage[0][0]);
            __syncthreads();                    // drain
            if (t < T_ - 1 && threadIdx.x == 0) setflag(flags, 2, js, t + 1);
        }
        if (kq == 0) {
            #pragma unroll
            for (int mi = 0; mi < 2; ++mi)
                #pragma unroll
                for (int r = 0; r < 4; ++r) {
                    int b = mh * 32 + mi * 16 + lq * 4 + r, j = js * 16 + lm;
                    h2f[b * H_ + j] = h_reg[mi][r]; c2f[b * H_ + j] = c_reg[mi][r];
                }
        }
    }
}

// ---------------- output fan-out ----------------
__global__ void write_out(const float* __restrict__ h1f, const float* __restrict__ h2f,
                          const float* __restrict__ c1f, const float* __restrict__ c2f,
                          float* __restrict__ out) {
    const long long EQ = (long long)B_ * H_ * 784;      // 51,380,224
    const long long n4 = (EQ + 4LL * B_ * H_) / 4;      // 12,910,592
    long long i4 = (long long)blockIdx.x * blockDim.x + threadIdx.x;
    long long stride = (long long)gridDim.x * blockDim.x;
    for (; i4 < n4; i4 += stride) {
        long long f = i4 * 4;
        float4 v;
        if (f < EQ) {
            long long bh = f / 784;
            float val = h2f[bh];
            v = make_float4(val, val, val, val);
        } else {
            long long r = f - EQ;
            int which = (int)(r >> 16);
            int j = (int)(r & 65535);
            const float* src = (which == 0) ? h1f : (which == 1) ? h2f : (which == 2) ? c1f : c2f;
            v = *reinterpret_cast<const float4*>(src + j);
        }
        reinterpret_cast<float4*>(out)[i4] = v;
    }
}

// ---------------- launch ----------------
extern "C" void kernel_launch(void* const* d_in, const int* in_sizes, int n_in,
                              void* d_out, int out_size, void* d_ws, size_t ws_size,
                              hipStream_t stream) {
    const int*   questions = (const int*)d_in[0];
    const int*   qlen      = (const int*)d_in[1];
    const float* embed     = (const float*)d_in[2];
    const float* W_ih1     = (const float*)d_in[3];
    const float* W_hh1     = (const float*)d_in[4];
    const float* b_ih1     = (const float*)d_in[5];
    const float* b_hh1     = (const float*)d_in[6];
    const float* W_ih2     = (const float*)d_in[7];
    const float* W_hh2     = (const float*)d_in[8];
    const float* b_ih2     = (const float*)d_in[9];
    const float* b_hh2     = (const float*)d_in[10];
    float* out = (float*)d_out;

    char* w = (char*)d_ws;
    float*    xg     = (float*)(w + 0);                 // 33,554,432
    ushort_t* Wih1p  = (ushort_t*)(w + 33554432);       //  2,621,440
    ushort_t* Xp     = (ushort_t*)(w + 36175872);       //  1,310,720
    ushort_t* h1hist = (ushort_t*)(w + 37486592);       // 33*131,072 = 4,325,376
    ushort_t* h2hist = (ushort_t*)(w + 41811968);       // 33*131,072 = 4,325,376
    float*    Qhist  = (float*)(w + 46137344);          // 32*1,048,576 = 33,554,432
    float*    h1f    = (float*)(w + 79691776);          //    262,144
    float*    c1f    = (float*)(w + 79953920);
    float*    h2f    = (float*)(w + 80216064);
    float*    c2f    = (float*)(w + 80478208);          // end 80,740,352
    int*      flags  = (int*)(w + 80740352);            // 12,288 -> end 80,752,640

    // all zero-init folded into prep_inputs -> zero memset dispatches
    prep_inputs<<<3395, 256, 0, stream>>>(questions, embed, Xp, W_ih1, Wih1p,
                                          h1hist, h2hist, flags);
    xgemm<<<dim3(32, 64), 256, 0, stream>>>(Xp, Wih1p, b_ih1, b_hh1, xg);

    lstm_persist<<<NBLK, 512, 0, stream>>>(W_hh1, W_ih2, W_hh2, b_ih2, b_hh2,
                                           xg, qlen,
                                           h1hist, h2hist, Qhist,
                                           h1f, c1f, h2f, c2f, flags);

    write_out<<<4096, 256, 0, stream>>>(h1f, h2f, c1f, c2f, out);
}

// Round 11
// 607.850 us; speedup vs baseline: 1.1961x; 1.1961x over previous
//
#include <hip/hip_runtime.h>
#include <hip/hip_bf16.h>
#include <cstdint>

#define B_  64
#define T_  32
#define E_  300
#define EP  320      // padded K for the x-precompute GEMM
#define H_  1024
#define G4  4096     // 4*H
#define BH  65536    // B_*H_
#define NBLK 192     // persistent blocks: 64 L1 + 64 I2 + 64 H2

// out layout: EQ [64][1024][28][28], then h1, h2, c1, c2 [64][1024] each
#define EQOFF 0LL
#define H1OFF 51380224LL
#define H2OFF 51445760LL
#define C1OFF 51511296LL
#define C2OFF 51576832LL

typedef __attribute__((ext_vector_type(8))) short bf16x8;
typedef __attribute__((ext_vector_type(4))) float f32x4;
typedef unsigned short ushort_t;

__device__ __forceinline__ bf16x8 load_b8(const ushort_t* p) {
    union { uint4 u; bf16x8 v; } c;
    c.u = *reinterpret_cast<const uint4*>(p);
    return c.v;
}

__device__ __forceinline__ ushort_t f2bf(float x) {
    union { float f; uint32_t u; } c; c.f = x;
    uint32_t r = c.u + 0x7fffu + ((c.u >> 16) & 1u);   // RNE
    return (ushort_t)(r >> 16);
}

__device__ __forceinline__ float sigm(float x) { return 1.0f / (1.0f + __expf(-x)); }

// agent-scope (cross-XCD write-through) stores for produced data; plain loads
// on the consumer side (unique buffer per timestep => no stale lines)
__device__ __forceinline__ void astore64(uint64_t* p, uint64_t v) {
    __hip_atomic_store(p, v, __ATOMIC_RELAXED, __HIP_MEMORY_SCOPE_AGENT);
}
__device__ __forceinline__ uint64_t packf2(float a, float b) {
    union { float f[2]; uint64_t u; } c; c.f[0] = a; c.f[1] = b; return c.u;
}

// ---- contention-free dataflow flags ----
__device__ __forceinline__ void setflag(int* flags, int role, int js, int val) {
    __hip_atomic_store(&flags[(role * 64 + js) * 16], val,
                       __ATOMIC_RELAXED, __HIP_MEMORY_SCOPE_AGENT);
}
__device__ __forceinline__ void waitwave(const int* flags, int role, int target, int lane) {
    const int* p = &flags[(role * 64 + lane) * 16];
    int guard = 0;
    for (;;) {
        int v = __hip_atomic_load(p, __ATOMIC_RELAXED, __HIP_MEMORY_SCOPE_AGENT);
        if (__all(v >= target)) return;
        if (++guard > (1 << 22)) return;        // diagnostic bail-out (never hit when healthy)
        __builtin_amdgcn_s_sleep(1);
    }
}

// ---------------- fused prep kernel ----------------
// [0,1280): embed gather+pad ; [1280,3328): W_ih1 pad+convert ;
// [3328,3392): zero h1hist/h2hist slot 0 ; [3392,3395): zero flags
__global__ void prep_inputs(const int* __restrict__ q, const float* __restrict__ table,
                            ushort_t* __restrict__ Xp,
                            const float* __restrict__ Wsrc, ushort_t* __restrict__ Wdst,
                            ushort_t* __restrict__ h1s0, ushort_t* __restrict__ h2s0,
                            int* __restrict__ flags) {
    int blk = blockIdx.x;
    if (blk < 1280) {
        int i = blk * 256 + threadIdx.x;
        const int n = B_ * T_ * EP;
        for (; i < n; i += 1280 * 256) {
            int r = i / EP, c = i - r * EP;
            Xp[i] = (c < E_) ? f2bf(table[q[r] * E_ + c]) : (ushort_t)0;
        }
    } else if (blk < 3328) {
        int i = (blk - 1280) * 256 + threadIdx.x;
        const int n = G4 * EP;
        for (; i < n; i += 2048 * 256) {
            int r = i / EP, c = i - r * EP;
            Wdst[i] = (c < E_) ? f2bf(Wsrc[r * E_ + c]) : (ushort_t)0;
        }
    } else if (blk < 3392) {
        int i = (blk - 3328) * 256 + threadIdx.x;       // 0..16383 uint4
        uint4 z = make_uint4(0, 0, 0, 0);
        if (i < 8192) reinterpret_cast<uint4*>(h1s0)[i] = z;
        else          reinterpret_cast<uint4*>(h2s0)[i - 8192] = z;
    } else {
        int i = (blk - 3392) * 256 + threadIdx.x;       // 0..767 uint4 = 12,288 B
        reinterpret_cast<uint4*>(flags)[i] = make_uint4(0, 0, 0, 0);
    }
}

// ---------------- x-part precompute GEMM ----------------
// xg[t][b][j][4gates] fp32 (gate-interleaved) -> role-0 reads ONE uint4/(b,j)
__launch_bounds__(256)
__global__ void xgemm(const ushort_t* __restrict__ Xp, const ushort_t* __restrict__ Wp,
                      const float* __restrict__ b_ih1, const float* __restrict__ b_hh1,
                      float* __restrict__ xg) {
    int mblk = blockIdx.x, nblk = blockIdx.y;
    int wave = threadIdx.x >> 6, lane = threadIdx.x & 63;
    int lm = lane & 15, lq = lane >> 4;
    int m0 = mblk * 64 + wave * 16;
    f32x4 acc[4];
    #pragma unroll
    for (int g = 0; g < 4; ++g) {
        int n = nblk * 64 + g * 16 + lm;
        float bv = b_ih1[n] + b_hh1[n];
        acc[g] = (f32x4){bv, bv, bv, bv};
    }
    for (int k0 = 0; k0 < EP; k0 += 32) {
        bf16x8 a = load_b8(Xp + (m0 + lm) * EP + k0 + lq * 8);
        #pragma unroll
        for (int g = 0; g < 4; ++g) {
            bf16x8 b = load_b8(Wp + (nblk * 64 + g * 16 + lm) * EP + k0 + lq * 8);
            acc[g] = __builtin_amdgcn_mfma_f32_16x16x32_bf16(a, b, acc[g], 0, 0, 0);
        }
    }
    #pragma unroll
    for (int g = 0; g < 4; ++g)
        #pragma unroll
        for (int r = 0; r < 4; ++r) {
            int m = m0 + lq * 4 + r;          // m = b*T + t
            int b = m >> 5, t = m & 31;
            int n = nblk * 64 + g * 16 + lm;  // raw 4H index
            int gate = n >> 10, j = n & 1023;
            xg[(((size_t)t * B_ + b) * H_ + j) * 4 + gate] = acc[g][r];
        }
}

// ---------------- persistent recurrence kernel (round-9 structure) ----------------
// 8 waves/block (512 thr) = 2 waves/SIMD. wave w: mi = w&3 (m-rows mi*16..+16),
// kh = w>>2 (K-half kh*512..+512). kh1 partials reduced via LDS into kh0.
// NEW: output fan-out is fused — when sample b freezes (qlen[b]==t+1), its
// EQ broadcast tile and h/c rows are streamed to `out` immediately, after the
// flag publish so the HBM drain overlaps the next step's wait.

__device__ __forceinline__ void gemm_half(const ushort_t* __restrict__ hslot,
                                          const ushort_t* __restrict__ wsf,
                                          int lm, int lq, int m0, int kh, f32x4 acc[4]) {
    const uint4* hr = reinterpret_cast<const uint4*>(hslot);
    const int rbase = (m0 + lm) * 2 + (lq & 1);
    const int cbo = lq >> 1;
    const int cb0 = kh * 32;                 // 16-col chunks per K-half
    uint4 buf[16];
    #pragma unroll
    for (int grp = 0; grp < 2; ++grp)
        #pragma unroll
        for (int i = 0; i < 8; ++i)
            buf[grp * 8 + i] = hr[(cb0 + grp * 16 + i * 2 + cbo) * 128 + rbase];
    #pragma unroll
    for (int grp = 0; grp < 2; ++grp)
        #pragma unroll
        for (int i = 0; i < 8; ++i) {
            int k0 = kh * 512 + grp * 256 + i * 32;
            union { uint4 u; bf16x8 v; } a; a.u = buf[grp * 8 + i];
            #pragma unroll
            for (int g = 0; g < 4; ++g) {
                int row = g * 16 + lm;
                bf16x8 bb = load_b8(wsf + row * 1024 + ((k0 + lq * 8) ^ ((lm & 7) << 3)));
                acc[g] = __builtin_amdgcn_mfma_f32_16x16x32_bf16(a.v, bb, acc[g], 0, 0, 0);
            }
        }
}

__device__ __forceinline__ void lstm_elem(const f32x4 acc[4], int r,
                                          float* c, float* h, ushort_t* hb) {
    float iv = sigm(acc[0][r]);
    float fv = sigm(acc[1][r]);
    float gv = tanhf(acc[2][r]);
    float ov = sigm(acc[3][r]);
    float cn = fv * c[r] + iv * gv;
    float hv = ov * tanhf(cn);
    c[r] = cn; h[r] = hv; hb[r] = f2bf(hv);
}

// col-major h-tile store: ONE contiguous 2KB burst per block (threads 0..255)
__device__ __forceinline__ void store_h_tile(ushort_t* slot, int js, const ushort_t* hst) {
    int tid = threadIdx.x;                     // caller guards tid < 256
    uint64_t v = reinterpret_cast<const uint64_t*>(hst)[tid];
    astore64(reinterpret_cast<uint64_t*>(slot) + js * 256 + tid, v);
}

__global__ __launch_bounds__(512) void lstm_persist(
    const float* __restrict__ Whh1, const float* __restrict__ Wih2,
    const float* __restrict__ Whh2,
    const float* __restrict__ b_ih2, const float* __restrict__ b_hh2,
    const float* __restrict__ xg, const int* __restrict__ qlen,
    ushort_t* __restrict__ h1hist,   // 33 slots of BH bf16, col-major; slot k = h1(k-1)
    ushort_t* __restrict__ h2hist,   // 33 slots of BH bf16, col-major; slot k = h2(k-1)
    float* __restrict__ Qhist,       // 32 slots of BH*4 fp32, gate-interleaved [b][j][4]
    float* __restrict__ out,
    int* __restrict__ flags)
{
    __shared__ ushort_t ws[64 * 1024];             // 131,072 B (swizzled)
    __shared__ __align__(16) ushort_t hstage[64][16];  // 2,048 B
    __shared__ f32x4 pacc[256][4];                 // 16,384 B
    __shared__ float hstage32[64][16];             // 4,096 B (fp32 h2 for EQ)
    __shared__ int qlen_sh[64];                    // 256 B  -> total ~154 KB, 1 blk/CU

    const int blk  = blockIdx.x;
    const int role = blk >> 6;          // 0=L1, 1=I2, 2=H2
    const int js   = blk & 63;
    const int w    = threadIdx.x >> 6, lane = threadIdx.x & 63;
    const int mi   = w & 3, kh = w >> 2;
    const int lm = lane & 15, lq = lane >> 4;
    const int m0 = mi * 16;
    const int pidx = mi * 64 + lane;

    if (threadIdx.x < 64) qlen_sh[threadIdx.x] = qlen[threadIdx.x];

    // ---- stage weight slice fp32 -> bf16 into LDS (once, swizzled) ----
    const float* Wsrc = (role == 0) ? Whh1 : (role == 1) ? Wih2 : Whh2;
    uint2* wsp = reinterpret_cast<uint2*>(ws);
    for (int idx = threadIdx.x; idx < 64 * 256; idx += 512) {
        int r = idx >> 8, c4 = idx & 255;
        int grow = (r >> 4) * H_ + js * 16 + (r & 15);
        float4 v = reinterpret_cast<const float4*>(Wsrc + (size_t)grow * H_)[c4];
        uint2 pk;
        pk.x = (uint32_t)f2bf(v.x) | ((uint32_t)f2bf(v.y) << 16);
        pk.y = (uint32_t)f2bf(v.z) | ((uint32_t)f2bf(v.w) << 16);
        wsp[r * 256 + (c4 ^ ((r & 7) << 1))] = pk;   // 8B-unit XOR == byte^((r&7)<<4)
    }
    __syncthreads();

    int q[4];
    #pragma unroll
    for (int r = 0; r < 4; ++r) q[r] = qlen_sh[m0 + lq * 4 + r];

    float    c_reg[4]  = {0.f, 0.f, 0.f, 0.f};
    float    h_reg[4]  = {0.f, 0.f, 0.f, 0.f};
    ushort_t hb_reg[4] = {0, 0, 0, 0};

    if (role == 0) {
        for (int t = 0; t < T_; ++t) {
            f32x4 acc[4];
            #pragma unroll
            for (int g = 0; g < 4; ++g) acc[g] = (f32x4){0.f, 0.f, 0.f, 0.f};
            if (kh == 0) {                      // xg loads issue before the wait
                uint4 xq[4];
                #pragma unroll
                for (int r = 0; r < 4; ++r)
                    xq[r] = reinterpret_cast<const uint4*>(xg)
                            [((size_t)t * B_ + (m0 + lq * 4 + r)) * H_ + js * 16 + lm];
                #pragma unroll
                for (int r = 0; r < 4; ++r) {
                    union { uint32_t u; float f; } x0, x1, x2, x3;
                    x0.u = xq[r].x; x1.u = xq[r].y; x2.u = xq[r].z; x3.u = xq[r].w;
                    acc[0][r] = x0.f; acc[1][r] = x1.f;
                    acc[2][r] = x2.f; acc[3][r] = x3.f;
                }
            }
            if (t > 0) {
                if (w == 0) waitwave(flags, 0, t, lane);   // h1 slot t complete
                __syncthreads();
            }
            gemm_half(h1hist + (size_t)t * BH, ws, lm, lq, m0, kh, acc);
            if (kh == 1) {
                #pragma unroll
                for (int g = 0; g < 4; ++g) pacc[pidx][g] = acc[g];
            }
            __syncthreads();
            if (kh == 0) {
                #pragma unroll
                for (int g = 0; g < 4; ++g) acc[g] += pacc[pidx][g];
                #pragma unroll
                for (int r = 0; r < 4; ++r) {
                    if (t < q[r]) lstm_elem(acc, r, c_reg, h_reg, hb_reg);
                    hstage[m0 + lq * 4 + r][lm] = hb_reg[r];
                }
            }
            __syncthreads();
            if (threadIdx.x < 256)
                store_h_tile(h1hist + (size_t)(t + 1) * BH, js, &hstage[0][0]);
            __syncthreads();                    // drains vmcnt: stores visible
            if (threadIdx.x == 0) setflag(flags, 0, js, t + 1);
            // fused output: h1/c1 rows for samples freezing this step
            if (kh == 0) {
                #pragma unroll
                for (int r = 0; r < 4; ++r) {
                    if (q[r] == t + 1) {
                        int b = m0 + lq * 4 + r, j = js * 16 + lm;
                        out[H1OFF + b * H_ + j] = h_reg[r];
                        out[C1OFF + b * H_ + j] = c_reg[r];
                    }
                }
            }
        }
    } else if (role == 1) {
        float bi[4];
        #pragma unroll
        for (int g = 0; g < 4; ++g) {
            int n = g * H_ + js * 16 + lm;
            bi[g] = b_ih2[n] + b_hh2[n];
        }
        for (int t = 0; t < T_; ++t) {
            if (w == 0) waitwave(flags, 0, t + 1, lane);   // h1 slot t+1 complete
            __syncthreads();
            f32x4 acc[4];
            #pragma unroll
            for (int g = 0; g < 4; ++g)
                acc[g] = (kh == 0) ? (f32x4){bi[g], bi[g], bi[g], bi[g]}
                                   : (f32x4){0.f, 0.f, 0.f, 0.f};
            gemm_half(h1hist + (size_t)(t + 1) * BH, ws, lm, lq, m0, kh, acc);
            if (kh == 1) {
                #pragma unroll
                for (int g = 0; g < 4; ++g) pacc[pidx][g] = acc[g];
            }
            __syncthreads();
            if (kh == 0) {
                #pragma unroll
                for (int g = 0; g < 4; ++g) acc[g] += pacc[pidx][g];
                uint64_t* Qw64 = (uint64_t*)(Qhist + (size_t)t * (4 * BH));
                #pragma unroll
                for (int r = 0; r < 4; ++r) {
                    int b = m0 + lq * 4 + r, j = js * 16 + lm;
                    size_t base = ((size_t)b * H_ + j) * 2;
                    astore64(Qw64 + base,     packf2(acc[0][r], acc[1][r]));
                    astore64(Qw64 + base + 1, packf2(acc[2][r], acc[3][r]));
                }
            }
            __syncthreads();                    // drain
            if (threadIdx.x == 0) setflag(flags, 1, js, t + 1);
        }
    } else {
        for (int t = 0; t < T_; ++t) {
            if (w == 0)               waitwave(flags, 1, t + 1, lane); // Q slot t done
            else if (w == 1 && t > 0) waitwave(flags, 2, t,     lane); // h2 slot t done
            __syncthreads();
            uint4 qp[4];
            if (kh == 0) {                      // Q loads complete under the GEMM
                const uint4* Qr = (const uint4*)(Qhist + (size_t)t * (4 * BH));
                #pragma unroll
                for (int r = 0; r < 4; ++r)
                    qp[r] = Qr[(size_t)(m0 + lq * 4 + r) * H_ + js * 16 + lm];
            }
            f32x4 acc[4];
            #pragma unroll
            for (int g = 0; g < 4; ++g) acc[g] = (f32x4){0.f, 0.f, 0.f, 0.f};
            gemm_half(h2hist + (size_t)t * BH, ws, lm, lq, m0, kh, acc);
            if (kh == 1) {
                #pragma unroll
                for (int g = 0; g < 4; ++g) pacc[pidx][g] = acc[g];
            }
            __syncthreads();
            if (kh == 0) {
                #pragma unroll
                for (int g = 0; g < 4; ++g) acc[g] += pacc[pidx][g];
                #pragma unroll
                for (int r = 0; r < 4; ++r) {
                    union { uint32_t u; float f; } x0, x1, x2, x3;
                    x0.u = qp[r].x; x1.u = qp[r].y; x2.u = qp[r].z; x3.u = qp[r].w;
                    acc[0][r] += x0.f; acc[1][r] += x1.f;
                    acc[2][r] += x2.f; acc[3][r] += x3.f;
                }
                #pragma unroll
                for (int r = 0; r < 4; ++r) {
                    if (t < q[r]) lstm_elem(acc, r, c_reg, h_reg, hb_reg);
                    hstage[m0 + lq * 4 + r][lm] = hb_reg[r];
                    hstage32[m0 + lq * 4 + r][lm] = h_reg[r];
                }
            }
            __syncthreads();
            if (threadIdx.x < 256)
                store_h_tile(h2hist + (size_t)(t + 1) * BH, js, &hstage[0][0]);
            __syncthreads();                    // drain
            if (t < T_ - 1 && threadIdx.x == 0) setflag(flags, 2, js, t + 1);
            // fused output: h2/c2 rows + cooperative EQ broadcast for frozen samples
            if (kh == 0) {
                #pragma unroll
                for (int r = 0; r < 4; ++r) {
                    if (q[r] == t + 1) {
                        int b = m0 + lq * 4 + r, j = js * 16 + lm;
                        out[H2OFF + b * H_ + j] = h_reg[r];
                        out[C2OFF + b * H_ + j] = c_reg[r];
                    }
                }
            }
            for (int b = 0; b < B_; ++b) {
                if (qlen_sh[b] != t + 1) continue;
                float4* dst = reinterpret_cast<float4*>(
                    out + (size_t)b * (H_ * 784) + (size_t)js * 16 * 784);
                for (int idx = threadIdx.x; idx < 3136; idx += 512) {
                    int c = idx / 196, p4 = idx - c * 196;
                    float v = hstage32[b][c];
                    dst[c * 196 + p4] = make_float4(v, v, v, v);
                }
            }
        }
    }
}

// ---------------- launch ----------------
extern "C" void kernel_launch(void* const* d_in, const int* in_sizes, int n_in,
                              void* d_out, int out_size, void* d_ws, size_t ws_size,
                              hipStream_t stream) {
    const int*   questions = (const int*)d_in[0];
    const int*   qlen      = (const int*)d_in[1];
    const float* embed     = (const float*)d_in[2];
    const float* W_ih1     = (const float*)d_in[3];
    const float* W_hh1     = (const float*)d_in[4];
    const float* b_ih1     = (const float*)d_in[5];
    const float* b_hh1     = (const float*)d_in[6];
    const float* W_ih2     = (const float*)d_in[7];
    const float* W_hh2     = (const float*)d_in[8];
    const float* b_ih2     = (const float*)d_in[9];
    const float* b_hh2     = (const float*)d_in[10];
    float* out = (float*)d_out;

    char* w = (char*)d_ws;
    float*    xg     = (float*)(w + 0);                 // 33,554,432
    ushort_t* Wih1p  = (ushort_t*)(w + 33554432);       //  2,621,440
    ushort_t* Xp     = (ushort_t*)(w + 36175872);       //  1,310,720
    ushort_t* h1hist = (ushort_t*)(w + 37486592);       // 33*131,072 = 4,325,376
    ushort_t* h2hist = (ushort_t*)(w + 41811968);       // 33*131,072 = 4,325,376
    float*    Qhist  = (float*)(w + 46137344);          // 32*1,048,576 = 33,554,432
    int*      flags  = (int*)(w + 80740352);            // 12,288 -> end 80,752,640

    // all zero-init folded into prep_inputs -> zero memset dispatches
    prep_inputs<<<3395, 256, 0, stream>>>(questions, embed, Xp, W_ih1, Wih1p,
                                          h1hist, h2hist, flags);
    xgemm<<<dim3(32, 64), 256, 0, stream>>>(Xp, Wih1p, b_ih1, b_hh1, xg);

    lstm_persist<<<NBLK, 512, 0, stream>>>(W_hh1, W_ih2, W_hh2, b_ih2, b_hh2,
                                           xg, qlen,
                                           h1hist, h2hist, Qhist,
                                           out, flags);
}

// Round 12
// 548.702 us; speedup vs baseline: 1.3250x; 1.1078x over previous
//
#include <hip/hip_runtime.h>
#include <hip/hip_bf16.h>
#include <cstdint>

#define B_  64
#define T_  32
#define E_  300
#define EP  320      // padded K for the x-precompute GEMM
#define H_  1024
#define G4  4096     // 4*H
#define BH  65536    // B_*H_
#define NBLK 256     // 64 L1 + 64 I2 + 64 H2 + 64 EQ-writers (1 block/CU, all resident)

// out layout: EQ [64][1024][28][28], then h1, h2, c1, c2 [64][1024] each
#define EQOFF 0LL
#define H1OFF 51380224LL
#define H2OFF 51445760LL
#define C1OFF 51511296LL
#define C2OFF 51576832LL

typedef __attribute__((ext_vector_type(8))) short bf16x8;
typedef __attribute__((ext_vector_type(4))) float f32x4;
typedef unsigned short ushort_t;

__device__ __forceinline__ bf16x8 load_b8(const ushort_t* p) {
    union { uint4 u; bf16x8 v; } c;
    c.u = *reinterpret_cast<const uint4*>(p);
    return c.v;
}

__device__ __forceinline__ ushort_t f2bf(float x) {
    union { float f; uint32_t u; } c; c.f = x;
    uint32_t r = c.u + 0x7fffu + ((c.u >> 16) & 1u);   // RNE
    return (ushort_t)(r >> 16);
}

__device__ __forceinline__ float sigm(float x) { return 1.0f / (1.0f + __expf(-x)); }

// agent-scope (cross-XCD write-through) stores for produced data; plain loads
// on the consumer side (unique buffer per timestep/sample => no stale lines)
__device__ __forceinline__ void astore64(uint64_t* p, uint64_t v) {
    __hip_atomic_store(p, v, __ATOMIC_RELAXED, __HIP_MEMORY_SCOPE_AGENT);
}
__device__ __forceinline__ void astoref(float* p, float v) {
    __hip_atomic_store(p, v, __ATOMIC_RELAXED, __HIP_MEMORY_SCOPE_AGENT);
}
__device__ __forceinline__ uint64_t packf2(float a, float b) {
    union { float f[2]; uint64_t u; } c; c.f[0] = a; c.f[1] = b; return c.u;
}

// ---- contention-free dataflow flags ----
__device__ __forceinline__ void setflag(int* flags, int role, int js, int val) {
    __hip_atomic_store(&flags[(role * 64 + js) * 16], val,
                       __ATOMIC_RELAXED, __HIP_MEMORY_SCOPE_AGENT);
}
__device__ __forceinline__ void waitwave(const int* flags, int role, int target, int lane) {
    const int* p = &flags[(role * 64 + lane) * 16];
    int guard = 0;
    for (;;) {
        int v = __hip_atomic_load(p, __ATOMIC_RELAXED, __HIP_MEMORY_SCOPE_AGENT);
        if (__all(v >= target)) return;
        if (++guard > (1 << 22)) return;        // diagnostic bail-out (never hit when healthy)
        __builtin_amdgcn_s_sleep(1);
    }
}

// ---------------- fused prep kernel ----------------
// [0,1280): embed gather+pad ; [1280,3328): W_ih1 pad+convert ;
// [3328,3392): zero h1hist/h2hist slot 0 ; [3392,3395): zero flags
__global__ void prep_inputs(const int* __restrict__ q, const float* __restrict__ table,
                            ushort_t* __restrict__ Xp,
                            const float* __restrict__ Wsrc, ushort_t* __restrict__ Wdst,
                            ushort_t* __restrict__ h1s0, ushort_t* __restrict__ h2s0,
                            int* __restrict__ flags) {
    int blk = blockIdx.x;
    if (blk < 1280) {
        int i = blk * 256 + threadIdx.x;
        const int n = B_ * T_ * EP;
        for (; i < n; i += 1280 * 256) {
            int r = i / EP, c = i - r * EP;
            Xp[i] = (c < E_) ? f2bf(table[q[r] * E_ + c]) : (ushort_t)0;
        }
    } else if (blk < 3328) {
        int i = (blk - 1280) * 256 + threadIdx.x;
        const int n = G4 * EP;
        for (; i < n; i += 2048 * 256) {
            int r = i / EP, c = i - r * EP;
            Wdst[i] = (c < E_) ? f2bf(Wsrc[r * E_ + c]) : (ushort_t)0;
        }
    } else if (blk < 3392) {
        int i = (blk - 3328) * 256 + threadIdx.x;       // 0..16383 uint4
        uint4 z = make_uint4(0, 0, 0, 0);
        if (i < 8192) reinterpret_cast<uint4*>(h1s0)[i] = z;
        else          reinterpret_cast<uint4*>(h2s0)[i - 8192] = z;
    } else {
        int i = (blk - 3392) * 256 + threadIdx.x;       // 0..767 uint4 = 12,288 B
        reinterpret_cast<uint4*>(flags)[i] = make_uint4(0, 0, 0, 0);
    }
}

// ---------------- x-part precompute GEMM ----------------
// xg[t][b][j][4gates] fp32 (gate-interleaved) -> role-0 reads ONE uint4/(b,j)
__launch_bounds__(256)
__global__ void xgemm(const ushort_t* __restrict__ Xp, const ushort_t* __restrict__ Wp,
                      const float* __restrict__ b_ih1, const float* __restrict__ b_hh1,
                      float* __restrict__ xg) {
    int mblk = blockIdx.x, nblk = blockIdx.y;
    int wave = threadIdx.x >> 6, lane = threadIdx.x & 63;
    int lm = lane & 15, lq = lane >> 4;
    int m0 = mblk * 64 + wave * 16;
    f32x4 acc[4];
    #pragma unroll
    for (int g = 0; g < 4; ++g) {
        int n = nblk * 64 + g * 16 + lm;
        float bv = b_ih1[n] + b_hh1[n];
        acc[g] = (f32x4){bv, bv, bv, bv};
    }
    for (int k0 = 0; k0 < EP; k0 += 32) {
        bf16x8 a = load_b8(Xp + (m0 + lm) * EP + k0 + lq * 8);
        #pragma unroll
        for (int g = 0; g < 4; ++g) {
            bf16x8 b = load_b8(Wp + (nblk * 64 + g * 16 + lm) * EP + k0 + lq * 8);
            acc[g] = __builtin_amdgcn_mfma_f32_16x16x32_bf16(a, b, acc[g], 0, 0, 0);
        }
    }
    #pragma unroll
    for (int g = 0; g < 4; ++g)
        #pragma unroll
        for (int r = 0; r < 4; ++r) {
            int m = m0 + lq * 4 + r;          // m = b*T + t
            int b = m >> 5, t = m & 31;
            int n = nblk * 64 + g * 16 + lm;  // raw 4H index
            int gate = n >> 10, j = n & 1023;
            xg[(((size_t)t * B_ + b) * H_ + j) * 4 + gate] = acc[g][r];
        }
}

// ---------------- persistent recurrence kernel ----------------
// 8 waves/block (512 thr). wave w: mi = w&3 (m-rows), kh = w>>2 (K-half).
// roles 0-2 as round 9 (persist=220us). Role 3 = EQ WRITER blocks: poll role-2
// block js's flag; when sample b freezes, stream its js-slice of the 784-fold
// EQ broadcast from the fp32 h2f row — OFF the recurrence chain (round-11's
// inline EQ emit serialized 200MB into the chain via the next vmcnt drain).

__device__ __forceinline__ void gemm_half(const ushort_t* __restrict__ hslot,
                                          const ushort_t* __restrict__ wsf,
                                          int lm, int lq, int m0, int kh, f32x4 acc[4]) {
    const uint4* hr = reinterpret_cast<const uint4*>(hslot);
    const int rbase = (m0 + lm) * 2 + (lq & 1);
    const int cbo = lq >> 1;
    const int cb0 = kh * 32;                 // 16-col chunks per K-half
    uint4 buf[16];
    #pragma unroll
    for (int grp = 0; grp < 2; ++grp)
        #pragma unroll
        for (int i = 0; i < 8; ++i)
            buf[grp * 8 + i] = hr[(cb0 + grp * 16 + i * 2 + cbo) * 128 + rbase];
    #pragma unroll
    for (int grp = 0; grp < 2; ++grp)
        #pragma unroll
        for (int i = 0; i < 8; ++i) {
            int k0 = kh * 512 + grp * 256 + i * 32;
            union { uint4 u; bf16x8 v; } a; a.u = buf[grp * 8 + i];
            #pragma unroll
            for (int g = 0; g < 4; ++g) {
                int row = g * 16 + lm;
                bf16x8 bb = load_b8(wsf + row * 1024 + ((k0 + lq * 8) ^ ((lm & 7) << 3)));
                acc[g] = __builtin_amdgcn_mfma_f32_16x16x32_bf16(a.v, bb, acc[g], 0, 0, 0);
            }
        }
}

__device__ __forceinline__ void lstm_elem(const f32x4 acc[4], int r,
                                          float* c, float* h, ushort_t* hb) {
    float iv = sigm(acc[0][r]);
    float fv = sigm(acc[1][r]);
    float gv = tanhf(acc[2][r]);
    float ov = sigm(acc[3][r]);
    float cn = fv * c[r] + iv * gv;
    float hv = ov * tanhf(cn);
    c[r] = cn; h[r] = hv; hb[r] = f2bf(hv);
}

// col-major h-tile store: ONE contiguous 2KB burst per block (threads 0..255)
__device__ __forceinline__ void store_h_tile(ushort_t* slot, int js, const ushort_t* hst) {
    int tid = threadIdx.x;                     // caller guards tid < 256
    uint64_t v = reinterpret_cast<const uint64_t*>(hst)[tid];
    astore64(reinterpret_cast<uint64_t*>(slot) + js * 256 + tid, v);
}

__global__ __launch_bounds__(512) void lstm_persist(
    const float* __restrict__ Whh1, const float* __restrict__ Wih2,
    const float* __restrict__ Whh2,
    const float* __restrict__ b_ih2, const float* __restrict__ b_hh2,
    const float* __restrict__ xg, const int* __restrict__ qlen,
    ushort_t* __restrict__ h1hist,   // 33 slots of BH bf16, col-major; slot k = h1(k-1)
    ushort_t* __restrict__ h2hist,   // 33 slots of BH bf16, col-major; slot k = h2(k-1)
    float* __restrict__ Qhist,       // 32 slots of BH*4 fp32, gate-interleaved [b][j][4]
    float* __restrict__ h2f,         // fp32 h2 rows for frozen samples (writer source)
    float* __restrict__ out,
    int* __restrict__ flags)
{
    __shared__ ushort_t ws[64 * 1024];             // 131,072 B (swizzled)
    __shared__ __align__(16) ushort_t hstage[64][16];  // 2,048 B
    __shared__ f32x4 pacc[256][4];                 // 16,384 B
    __shared__ int qlen_sh[64];                    // 256 B -> total 149,760 B, 1 blk/CU

    const int blk  = blockIdx.x;
    const int role = blk >> 6;          // 0=L1, 1=I2, 2=H2, 3=EQ writer
    const int js   = blk & 63;
    const int w    = threadIdx.x >> 6, lane = threadIdx.x & 63;
    const int mi   = w & 3, kh = w >> 2;
    const int lm = lane & 15, lq = lane >> 4;
    const int m0 = mi * 16;
    const int pidx = mi * 64 + lane;

    if (threadIdx.x < 64) qlen_sh[threadIdx.x] = qlen[threadIdx.x];

    if (role == 3) {
        // ---- EQ writer: off-chain output streaming ----
        __syncthreads();                            // qlen_sh ready
        for (int t = 0; t < T_; ++t) {
            bool any = false;
            for (int b = 0; b < B_; ++b) any |= (qlen_sh[b] == t + 1);
            if (!any) continue;
            if (threadIdx.x == 0) {                 // only role-2 block js matters
                const int* p = &flags[(2 * 64 + js) * 16];
                int guard = 0;
                while (__hip_atomic_load(p, __ATOMIC_RELAXED, __HIP_MEMORY_SCOPE_AGENT) < t + 1) {
                    if (++guard > (1 << 22)) break;
                    __builtin_amdgcn_s_sleep(1);
                }
            }
            __syncthreads();
            for (int b = 0; b < B_; ++b) {
                if (qlen_sh[b] != t + 1) continue;
                const float* src = h2f + (size_t)b * H_ + js * 16;
                float4* dst = reinterpret_cast<float4*>(
                    out + (size_t)b * (H_ * 784) + (size_t)js * 16 * 784);
                for (int idx = threadIdx.x; idx < 3136; idx += 512) {
                    int c = idx / 196, p4 = idx - c * 196;
                    float v = src[c];
                    dst[c * 196 + p4] = make_float4(v, v, v, v);
                }
            }
        }
        return;
    }

    // ---- stage weight slice fp32 -> bf16 into LDS (once, swizzled) ----
    const float* Wsrc = (role == 0) ? Whh1 : (role == 1) ? Wih2 : Whh2;
    uint2* wsp = reinterpret_cast<uint2*>(ws);
    for (int idx = threadIdx.x; idx < 64 * 256; idx += 512) {
        int r = idx >> 8, c4 = idx & 255;
        int grow = (r >> 4) * H_ + js * 16 + (r & 15);
        float4 v = reinterpret_cast<const float4*>(Wsrc + (size_t)grow * H_)[c4];
        uint2 pk;
        pk.x = (uint32_t)f2bf(v.x) | ((uint32_t)f2bf(v.y) << 16);
        pk.y = (uint32_t)f2bf(v.z) | ((uint32_t)f2bf(v.w) << 16);
        wsp[r * 256 + (c4 ^ ((r & 7) << 1))] = pk;   // 8B-unit XOR == byte^((r&7)<<4)
    }
    __syncthreads();

    int q[4];
    #pragma unroll
    for (int r = 0; r < 4; ++r) q[r] = qlen_sh[m0 + lq * 4 + r];

    float    c_reg[4]  = {0.f, 0.f, 0.f, 0.f};
    float    h_reg[4]  = {0.f, 0.f, 0.f, 0.f};
    ushort_t hb_reg[4] = {0, 0, 0, 0};

    if (role == 0) {
        for (int t = 0; t < T_; ++t) {
            f32x4 acc[4];
            #pragma unroll
            for (int g = 0; g < 4; ++g) acc[g] = (f32x4){0.f, 0.f, 0.f, 0.f};
            if (kh == 0) {                      // xg loads issue before the wait
                uint4 xq[4];
                #pragma unroll
                for (int r = 0; r < 4; ++r)
                    xq[r] = reinterpret_cast<const uint4*>(xg)
                            [((size_t)t * B_ + (m0 + lq * 4 + r)) * H_ + js * 16 + lm];
                #pragma unroll
                for (int r = 0; r < 4; ++r) {
                    union { uint32_t u; float f; } x0, x1, x2, x3;
                    x0.u = xq[r].x; x1.u = xq[r].y; x2.u = xq[r].z; x3.u = xq[r].w;
                    acc[0][r] = x0.f; acc[1][r] = x1.f;
                    acc[2][r] = x2.f; acc[3][r] = x3.f;
                }
            }
            if (t > 0) {
                if (w == 0) waitwave(flags, 0, t, lane);   // h1 slot t complete
                __syncthreads();
            }
            gemm_half(h1hist + (size_t)t * BH, ws, lm, lq, m0, kh, acc);
            if (kh == 1) {
                #pragma unroll
                for (int g = 0; g < 4; ++g) pacc[pidx][g] = acc[g];
            }
            __syncthreads();
            if (kh == 0) {
                #pragma unroll
                for (int g = 0; g < 4; ++g) acc[g] += pacc[pidx][g];
                #pragma unroll
                for (int r = 0; r < 4; ++r) {
                    if (t < q[r]) lstm_elem(acc, r, c_reg, h_reg, hb_reg);
                    hstage[m0 + lq * 4 + r][lm] = hb_reg[r];
                    if (q[r] == t + 1) {        // sample froze: emit finals (tiny)
                        int b = m0 + lq * 4 + r, j = js * 16 + lm;
                        out[H1OFF + b * H_ + j] = h_reg[r];
                        out[C1OFF + b * H_ + j] = c_reg[r];
                    }
                }
            }
            __syncthreads();
            if (threadIdx.x < 256)
                store_h_tile(h1hist + (size_t)(t + 1) * BH, js, &hstage[0][0]);
            __syncthreads();                    // drains vmcnt: stores visible
            if (threadIdx.x == 0) setflag(flags, 0, js, t + 1);
        }
    } else if (role == 1) {
        float bi[4];
        #pragma unroll
        for (int g = 0; g < 4; ++g) {
            int n = g * H_ + js * 16 + lm;
            bi[g] = b_ih2[n] + b_hh2[n];
        }
        for (int t = 0; t < T_; ++t) {
            if (w == 0) waitwave(flags, 0, t + 1, lane);   // h1 slot t+1 complete
            __syncthreads();
            f32x4 acc[4];
            #pragma unroll
            for (int g = 0; g < 4; ++g)
                acc[g] = (kh == 0) ? (f32x4){bi[g], bi[g], bi[g], bi[g]}
                                   : (f32x4){0.f, 0.f, 0.f, 0.f};
            gemm_half(h1hist + (size_t)(t + 1) * BH, ws, lm, lq, m0, kh, acc);
            if (kh == 1) {
                #pragma unroll
                for (int g = 0; g < 4; ++g) pacc[pidx][g] = acc[g];
            }
            __syncthreads();
            if (kh == 0) {
                #pragma unroll
                for (int g = 0; g < 4; ++g) acc[g] += pacc[pidx][g];
                uint64_t* Qw64 = (uint64_t*)(Qhist + (size_t)t * (4 * BH));
                #pragma unroll
                for (int r = 0; r < 4; ++r) {
                    int b = m0 + lq * 4 + r, j = js * 16 + lm;
                    size_t base = ((size_t)b * H_ + j) * 2;
                    astore64(Qw64 + base,     packf2(acc[0][r], acc[1][r]));
                    astore64(Qw64 + base + 1, packf2(acc[2][r], acc[3][r]));
                }
            }
            __syncthreads();                    // drain
            if (threadIdx.x == 0) setflag(flags, 1, js, t + 1);
        }
    } else {
        for (int t = 0; t < T_; ++t) {
            if (w == 0)               waitwave(flags, 1, t + 1, lane); // Q slot t done
            else if (w == 1 && t > 0) waitwave(flags, 2, t,     lane); // h2 slot t done
            __syncthreads();
            uint4 qp[4];
            if (kh == 0) {                      // Q loads complete under the GEMM
                const uint4* Qr = (const uint4*)(Qhist + (size_t)t * (4 * BH));
                #pragma unroll
                for (int r = 0; r < 4; ++r)
                    qp[r] = Qr[(size_t)(m0 + lq * 4 + r) * H_ + js * 16 + lm];
            }
            f32x4 acc[4];
            #pragma unroll
            for (int g = 0; g < 4; ++g) acc[g] = (f32x4){0.f, 0.f, 0.f, 0.f};
            gemm_half(h2hist + (size_t)t * BH, ws, lm, lq, m0, kh, acc);
            if (kh == 1) {
                #pragma unroll
                for (int g = 0; g < 4; ++g) pacc[pidx][g] = acc[g];
            }
            __syncthreads();
            if (kh == 0) {
                #pragma unroll
                for (int g = 0; g < 4; ++g) acc[g] += pacc[pidx][g];
                #pragma unroll
                for (int r = 0; r < 4; ++r) {
                    union { uint32_t u; float f; } x0, x1, x2, x3;
                    x0.u = qp[r].x; x1.u = qp[r].y; x2.u = qp[r].z; x3.u = qp[r].w;
                    acc[0][r] += x0.f; acc[1][r] += x1.f;
                    acc[2][r] += x2.f; acc[3][r] += x3.f;
                }
                #pragma unroll
                for (int r = 0; r < 4; ++r) {
                    if (t < q[r]) lstm_elem(acc, r, c_reg, h_reg, hb_reg);
                    hstage[m0 + lq * 4 + r][lm] = hb_reg[r];
                    if (q[r] == t + 1) {        // sample froze: publish fp32 h2 row
                        int b = m0 + lq * 4 + r, j = js * 16 + lm;
                        astoref(&h2f[(size_t)b * H_ + j], h_reg[r]);  // pre-drain => covered by flag2
                        out[H2OFF + b * H_ + j] = h_reg[r];
                        out[C2OFF + b * H_ + j] = c_reg[r];
                    }
                }
            }
            __syncthreads();
            if (threadIdx.x < 256)
                store_h_tile(h2hist + (size_t)(t + 1) * BH, js, &hstage[0][0]);
            __syncthreads();                    // drain (covers h2f stores too)
            if (threadIdx.x == 0) setflag(flags, 2, js, t + 1);  // ALL t (writers need 32)
        }
    }
}

// ---------------- launch ----------------
extern "C" void kernel_launch(void* const* d_in, const int* in_sizes, int n_in,
                              void* d_out, int out_size, void* d_ws, size_t ws_size,
                              hipStream_t stream) {
    const int*   questions = (const int*)d_in[0];
    const int*   qlen      = (const int*)d_in[1];
    const float* embed     = (const float*)d_in[2];
    const float* W_ih1     = (const float*)d_in[3];
    const float* W_hh1     = (const float*)d_in[4];
    const float* b_ih1     = (const float*)d_in[5];
    const float* b_hh1     = (const float*)d_in[6];
    const float* W_ih2     = (const float*)d_in[7];
    const float* W_hh2     = (const float*)d_in[8];
    const float* b_ih2     = (const float*)d_in[9];
    const float* b_hh2     = (const float*)d_in[10];
    float* out = (float*)d_out;

    char* w = (char*)d_ws;
    float*    xg     = (float*)(w + 0);                 // 33,554,432
    ushort_t* Wih1p  = (ushort_t*)(w + 33554432);       //  2,621,440
    ushort_t* Xp     = (ushort_t*)(w + 36175872);       //  1,310,720
    ushort_t* h1hist = (ushort_t*)(w + 37486592);       // 33*131,072 = 4,325,376
    ushort_t* h2hist = (ushort_t*)(w + 41811968);       // 33*131,072 = 4,325,376
    float*    Qhist  = (float*)(w + 46137344);          // 32*1,048,576 = 33,554,432
    float*    h2f    = (float*)(w + 80216064);          //    262,144 (writer source)
    int*      flags  = (int*)(w + 80740352);            // 12,288 -> end 80,752,640

    // all zero-init folded into prep_inputs -> zero memset dispatches
    prep_inputs<<<3395, 256, 0, stream>>>(questions, embed, Xp, W_ih1, Wih1p,
                                          h1hist, h2hist, flags);
    xgemm<<<dim3(32, 64), 256, 0, stream>>>(Xp, Wih1p, b_ih1, b_hh1, xg);

    lstm_persist<<<NBLK, 512, 0, stream>>>(W_hh1, W_ih2, W_hh2, b_ih2, b_hh2,
                                           xg, qlen,
                                           h1hist, h2hist, Qhist,
                                           h2f, out, flags);
}

// Round 14
// 541.422 us; speedup vs baseline: 1.3428x; 1.0134x over previous
//
#include <hip/hip_runtime.h>
#include <hip/hip_bf16.h>
#include <cstdint>

#define B_  64
#define T_  32
#define E_  300
#define EP  320      // padded K for the x-precompute GEMM
#define H_  1024
#define G4  4096     // 4*H
#define BH  65536    // B_*H_
#define NBLK 256     // 64 L1 + 64 I2 + 64 H2 + 64 EQ-writers (1 block/CU, all resident)

// out layout: EQ [64][1024][28][28], then h1, h2, c1, c2 [64][1024] each
#define EQOFF 0LL
#define H1OFF 51380224LL
#define H2OFF 51445760LL
#define C1OFF 51511296LL
#define C2OFF 51576832LL

typedef __attribute__((ext_vector_type(8))) short bf16x8;
typedef __attribute__((ext_vector_type(4))) float f32x4;
typedef unsigned short ushort_t;

__device__ __forceinline__ bf16x8 load_b8(const ushort_t* p) {
    union { uint4 u; bf16x8 v; } c;
    c.u = *reinterpret_cast<const uint4*>(p);
    return c.v;
}

__device__ __forceinline__ ushort_t f2bf(float x) {
    union { float f; uint32_t u; } c; c.f = x;
    uint32_t r = c.u + 0x7fffu + ((c.u >> 16) & 1u);   // RNE
    return (ushort_t)(r >> 16);
}

__device__ __forceinline__ float sigm(float x) { return 1.0f / (1.0f + __expf(-x)); }

// agent-scope (cross-XCD write-through) stores for produced data; plain loads
// on the consumer side (unique buffer per timestep/sample => no stale lines)
__device__ __forceinline__ void astore64(uint64_t* p, uint64_t v) {
    __hip_atomic_store(p, v, __ATOMIC_RELAXED, __HIP_MEMORY_SCOPE_AGENT);
}
__device__ __forceinline__ void astoref(float* p, float v) {
    __hip_atomic_store(p, v, __ATOMIC_RELAXED, __HIP_MEMORY_SCOPE_AGENT);
}
__device__ __forceinline__ uint64_t packf2(float a, float b) {
    union { float f[2]; uint64_t u; } c; c.f[0] = a; c.f[1] = b; return c.u;
}

// ---- contention-free dataflow flags ----
__device__ __forceinline__ void setflag(int* flags, int role, int js, int val) {
    __hip_atomic_store(&flags[(role * 64 + js) * 16], val,
                       __ATOMIC_RELAXED, __HIP_MEMORY_SCOPE_AGENT);
}
__device__ __forceinline__ void waitwave(const int* flags, int role, int target, int lane) {
    const int* p = &flags[(role * 64 + lane) * 16];
    int guard = 0;
    for (;;) {
        int v = __hip_atomic_load(p, __ATOMIC_RELAXED, __HIP_MEMORY_SCOPE_AGENT);
        if (__all(v >= target)) return;
        if (++guard > (1 << 22)) return;        // diagnostic bail-out (never hit when healthy)
        __builtin_amdgcn_s_sleep(1);
    }
}

// ---------------- fused prep kernel ----------------
// [0,1280): embed gather+pad ; [1280,3328): W_ih1 pad+convert ;
// [3328,3392): zero h1hist/h2hist slot 0 ; [3392,3395): zero flags
__global__ void prep_inputs(const int* __restrict__ q, const float* __restrict__ table,
                            ushort_t* __restrict__ Xp,
                            const float* __restrict__ Wsrc, ushort_t* __restrict__ Wdst,
                            ushort_t* __restrict__ h1s0, ushort_t* __restrict__ h2s0,
                            int* __restrict__ flags) {
    int blk = blockIdx.x;
    if (blk < 1280) {
        int i = blk * 256 + threadIdx.x;
        const int n = B_ * T_ * EP;
        for (; i < n; i += 1280 * 256) {
            int r = i / EP, c = i - r * EP;
            Xp[i] = (c < E_) ? f2bf(table[q[r] * E_ + c]) : (ushort_t)0;
        }
    } else if (blk < 3328) {
        int i = (blk - 1280) * 256 + threadIdx.x;
        const int n = G4 * EP;
        for (; i < n; i += 2048 * 256) {
            int r = i / EP, c = i - r * EP;
            Wdst[i] = (c < E_) ? f2bf(Wsrc[r * E_ + c]) : (ushort_t)0;
        }
    } else if (blk < 3392) {
        int i = (blk - 3328) * 256 + threadIdx.x;       // 0..16383 uint4
        uint4 z = make_uint4(0, 0, 0, 0);
        if (i < 8192) reinterpret_cast<uint4*>(h1s0)[i] = z;
        else          reinterpret_cast<uint4*>(h2s0)[i - 8192] = z;
    } else {
        int i = (blk - 3392) * 256 + threadIdx.x;       // 0..767 uint4 = 12,288 B
        reinterpret_cast<uint4*>(flags)[i] = make_uint4(0, 0, 0, 0);
    }
}

// ---------------- x-part precompute GEMM ----------------
// xg[t][b][j][4gates] fp32 (gate-interleaved) -> role-0 reads ONE uint4/(b,j)
__launch_bounds__(256)
__global__ void xgemm(const ushort_t* __restrict__ Xp, const ushort_t* __restrict__ Wp,
                      const float* __restrict__ b_ih1, const float* __restrict__ b_hh1,
                      float* __restrict__ xg) {
    int mblk = blockIdx.x, nblk = blockIdx.y;
    int wave = threadIdx.x >> 6, lane = threadIdx.x & 63;
    int lm = lane & 15, lq = lane >> 4;
    int m0 = mblk * 64 + wave * 16;
    f32x4 acc[4];
    #pragma unroll
    for (int g = 0; g < 4; ++g) {
        int n = nblk * 64 + g * 16 + lm;
        float bv = b_ih1[n] + b_hh1[n];
        acc[g] = (f32x4){bv, bv, bv, bv};
    }
    for (int k0 = 0; k0 < EP; k0 += 32) {
        bf16x8 a = load_b8(Xp + (m0 + lm) * EP + k0 + lq * 8);
        #pragma unroll
        for (int g = 0; g < 4; ++g) {
            bf16x8 b = load_b8(Wp + (nblk * 64 + g * 16 + lm) * EP + k0 + lq * 8);
            acc[g] = __builtin_amdgcn_mfma_f32_16x16x32_bf16(a, b, acc[g], 0, 0, 0);
        }
    }
    #pragma unroll
    for (int g = 0; g < 4; ++g)
        #pragma unroll
        for (int r = 0; r < 4; ++r) {
            int m = m0 + lq * 4 + r;          // m = b*T + t
            int b = m >> 5, t = m & 31;
            int n = nblk * 64 + g * 16 + lm;  // raw 4H index
            int gate = n >> 10, j = n & 1023;
            xg[(((size_t)t * B_ + b) * H_ + j) * 4 + gate] = acc[g][r];
        }
}

// ---------------- persistent recurrence kernel ----------------
// 8 waves/block (512 thr). wave w: mi = w&3 (m-rows), kh = w>>2 (K-half).
// roles 0-2 as round 9. Role 3 = EQ writer blocks (off-chain output stream).
// All final-output stores are NON-TEMPORAL (no L2 retention) — the EQ stream
// was thrashing each XCD's 4MB L2 (persist 220->274 when writers added).

__device__ __forceinline__ void gemm_half(const ushort_t* __restrict__ hslot,
                                          const ushort_t* __restrict__ wsf,
                                          int lm, int lq, int m0, int kh, f32x4 acc[4]) {
    const uint4* hr = reinterpret_cast<const uint4*>(hslot);
    const int rbase = (m0 + lm) * 2 + (lq & 1);
    const int cbo = lq >> 1;
    const int cb0 = kh * 32;                 // 16-col chunks per K-half
    uint4 buf[16];
    #pragma unroll
    for (int grp = 0; grp < 2; ++grp)
        #pragma unroll
        for (int i = 0; i < 8; ++i)
            buf[grp * 8 + i] = hr[(cb0 + grp * 16 + i * 2 + cbo) * 128 + rbase];
    #pragma unroll
    for (int grp = 0; grp < 2; ++grp)
        #pragma unroll
        for (int i = 0; i < 8; ++i) {
            int k0 = kh * 512 + grp * 256 + i * 32;
            union { uint4 u; bf16x8 v; } a; a.u = buf[grp * 8 + i];
            #pragma unroll
            for (int g = 0; g < 4; ++g) {
                int row = g * 16 + lm;
                bf16x8 bb = load_b8(wsf + row * 1024 + ((k0 + lq * 8) ^ ((lm & 7) << 3)));
                acc[g] = __builtin_amdgcn_mfma_f32_16x16x32_bf16(a.v, bb, acc[g], 0, 0, 0);
            }
        }
}

__device__ __forceinline__ void lstm_elem(const f32x4 acc[4], int r,
                                          float* c, float* h, ushort_t* hb) {
    float iv = sigm(acc[0][r]);
    float fv = sigm(acc[1][r]);
    float gv = tanhf(acc[2][r]);
    float ov = sigm(acc[3][r]);
    float cn = fv * c[r] + iv * gv;
    float hv = ov * tanhf(cn);
    c[r] = cn; h[r] = hv; hb[r] = f2bf(hv);
}

// col-major h-tile store: ONE contiguous 2KB burst per block (threads 0..255)
__device__ __forceinline__ void store_h_tile(ushort_t* slot, int js, const ushort_t* hst) {
    int tid = threadIdx.x;                     // caller guards tid < 256
    uint64_t v = reinterpret_cast<const uint64_t*>(hst)[tid];
    astore64(reinterpret_cast<uint64_t*>(slot) + js * 256 + tid, v);
}

__global__ __launch_bounds__(512) void lstm_persist(
    const float* __restrict__ Whh1, const float* __restrict__ Wih2,
    const float* __restrict__ Whh2,
    const float* __restrict__ b_ih2, const float* __restrict__ b_hh2,
    const float* __restrict__ xg, const int* __restrict__ qlen,
    ushort_t* __restrict__ h1hist,   // 33 slots of BH bf16, col-major; slot k = h1(k-1)
    ushort_t* __restrict__ h2hist,   // 33 slots of BH bf16, col-major; slot k = h2(k-1)
    float* __restrict__ Qhist,       // 32 slots of BH*4 fp32, gate-interleaved [b][j][4]
    float* __restrict__ h2f,         // fp32 h2 rows for frozen samples (writer source)
    float* __restrict__ out,
    int* __restrict__ flags)
{
    __shared__ ushort_t ws[64 * 1024];             // 131,072 B (swizzled)
    __shared__ __align__(16) ushort_t hstage[64][16];  // 2,048 B
    __shared__ f32x4 pacc[256][4];                 // 16,384 B
    __shared__ int qlen_sh[64];                    // 256 B -> total 149,760 B, 1 blk/CU

    const int blk  = blockIdx.x;
    const int role = blk >> 6;          // 0=L1, 1=I2, 2=H2, 3=EQ writer
    const int js   = blk & 63;
    const int w    = threadIdx.x >> 6, lane = threadIdx.x & 63;
    const int mi   = w & 3, kh = w >> 2;
    const int lm = lane & 15, lq = lane >> 4;
    const int m0 = mi * 16;
    const int pidx = mi * 64 + lane;

    if (threadIdx.x < 64) qlen_sh[threadIdx.x] = qlen[threadIdx.x];

    if (role == 3) {
        // ---- EQ writer: off-chain output streaming (non-temporal stores) ----
        __syncthreads();                            // qlen_sh ready
        for (int t = 0; t < T_; ++t) {
            bool any = false;
            for (int b = 0; b < B_; ++b) any |= (qlen_sh[b] == t + 1);
            if (!any) continue;
            if (threadIdx.x == 0) {                 // only role-2 block js matters
                const int* p = &flags[(2 * 64 + js) * 16];
                int guard = 0;
                while (__hip_atomic_load(p, __ATOMIC_RELAXED, __HIP_MEMORY_SCOPE_AGENT) < t + 1) {
                    if (++guard > (1 << 22)) break;
                    __builtin_amdgcn_s_sleep(1);
                }
            }
            __syncthreads();
            for (int b = 0; b < B_; ++b) {
                if (qlen_sh[b] != t + 1) continue;
                const float* src = h2f + (size_t)b * H_ + js * 16;
                f32x4* dst = reinterpret_cast<f32x4*>(
                    out + (size_t)b * (H_ * 784) + (size_t)js * 16 * 784);
                for (int idx = threadIdx.x; idx < 3136; idx += 512) {
                    int c = idx / 196, p4 = idx - c * 196;
                    float v = src[c];
                    f32x4 vv = (f32x4){v, v, v, v};
                    __builtin_nontemporal_store(vv, &dst[c * 196 + p4]);
                }
            }
        }
        return;
    }

    // ---- stage weight slice fp32 -> bf16 into LDS (once, swizzled) ----
    const float* Wsrc = (role == 0) ? Whh1 : (role == 1) ? Wih2 : Whh2;
    uint2* wsp = reinterpret_cast<uint2*>(ws);
    for (int idx = threadIdx.x; idx < 64 * 256; idx += 512) {
        int r = idx >> 8, c4 = idx & 255;
        int grow = (r >> 4) * H_ + js * 16 + (r & 15);
        float4 v = reinterpret_cast<const float4*>(Wsrc + (size_t)grow * H_)[c4];
        uint2 pk;
        pk.x = (uint32_t)f2bf(v.x) | ((uint32_t)f2bf(v.y) << 16);
        pk.y = (uint32_t)f2bf(v.z) | ((uint32_t)f2bf(v.w) << 16);
        wsp[r * 256 + (c4 ^ ((r & 7) << 1))] = pk;   // 8B-unit XOR == byte^((r&7)<<4)
    }
    __syncthreads();

    int q[4];
    #pragma unroll
    for (int r = 0; r < 4; ++r) q[r] = qlen_sh[m0 + lq * 4 + r];

    float    c_reg[4]  = {0.f, 0.f, 0.f, 0.f};
    float    h_reg[4]  = {0.f, 0.f, 0.f, 0.f};
    ushort_t hb_reg[4] = {0, 0, 0, 0};

    if (role == 0) {
        for (int t = 0; t < T_; ++t) {
            f32x4 acc[4];
            #pragma unroll
            for (int g = 0; g < 4; ++g) acc[g] = (f32x4){0.f, 0.f, 0.f, 0.f};
            if (kh == 0) {                      // xg loads issue before the wait
                uint4 xq[4];
                #pragma unroll
                for (int r = 0; r < 4; ++r)
                    xq[r] = reinterpret_cast<const uint4*>(xg)
                            [((size_t)t * B_ + (m0 + lq * 4 + r)) * H_ + js * 16 + lm];
                #pragma unroll
                for (int r = 0; r < 4; ++r) {
                    union { uint32_t u; float f; } x0, x1, x2, x3;
                    x0.u = xq[r].x; x1.u = xq[r].y; x2.u = xq[r].z; x3.u = xq[r].w;
                    acc[0][r] = x0.f; acc[1][r] = x1.f;
                    acc[2][r] = x2.f; acc[3][r] = x3.f;
                }
            }
            if (t > 0) {
                if (w == 0) waitwave(flags, 0, t, lane);   // h1 slot t complete
                __syncthreads();
            }
            gemm_half(h1hist + (size_t)t * BH, ws, lm, lq, m0, kh, acc);
            if (kh == 1) {
                #pragma unroll
                for (int g = 0; g < 4; ++g) pacc[pidx][g] = acc[g];
            }
            __syncthreads();
            if (kh == 0) {
                #pragma unroll
                for (int g = 0; g < 4; ++g) acc[g] += pacc[pidx][g];
                #pragma unroll
                for (int r = 0; r < 4; ++r) {
                    if (t < q[r]) lstm_elem(acc, r, c_reg, h_reg, hb_reg);
                    hstage[m0 + lq * 4 + r][lm] = hb_reg[r];
                    if (q[r] == t + 1) {        // sample froze: emit finals (tiny, nt)
                        int b = m0 + lq * 4 + r, j = js * 16 + lm;
                        __builtin_nontemporal_store(h_reg[r], &out[H1OFF + b * H_ + j]);
                        __builtin_nontemporal_store(c_reg[r], &out[C1OFF + b * H_ + j]);
                    }
                }
            }
            __syncthreads();
            if (threadIdx.x < 256)
                store_h_tile(h1hist + (size_t)(t + 1) * BH, js, &hstage[0][0]);
            __syncthreads();                    // drains vmcnt: stores visible
            if (threadIdx.x == 0) setflag(flags, 0, js, t + 1);
        }
    } else if (role == 1) {
        float bi[4];
        #pragma unroll
        for (int g = 0; g < 4; ++g) {
            int n = g * H_ + js * 16 + lm;
            bi[g] = b_ih2[n] + b_hh2[n];
        }
        for (int t = 0; t < T_; ++t) {
            if (w == 0) waitwave(flags, 0, t + 1, lane);   // h1 slot t+1 complete
            __syncthreads();
            f32x4 acc[4];
            #pragma unroll
            for (int g = 0; g < 4; ++g)
                acc[g] = (kh == 0) ? (f32x4){bi[g], bi[g], bi[g], bi[g]}
                                   : (f32x4){0.f, 0.f, 0.f, 0.f};
            gemm_half(h1hist + (size_t)(t + 1) * BH, ws, lm, lq, m0, kh, acc);
            if (kh == 1) {
                #pragma unroll
                for (int g = 0; g < 4; ++g) pacc[pidx][g] = acc[g];
            }
            __syncthreads();
            if (kh == 0) {
                #pragma unroll
                for (int g = 0; g < 4; ++g) acc[g] += pacc[pidx][g];
                uint64_t* Qw64 = (uint64_t*)(Qhist + (size_t)t * (4 * BH));
                #pragma unroll
                for (int r = 0; r < 4; ++r) {
                    int b = m0 + lq * 4 + r, j = js * 16 + lm;
                    size_t base = ((size_t)b * H_ + j) * 2;
                    astore64(Qw64 + base,     packf2(acc[0][r], acc[1][r]));
                    astore64(Qw64 + base + 1, packf2(acc[2][r], acc[3][r]));
                }
            }
            __syncthreads();                    // drain
            if (threadIdx.x == 0) setflag(flags, 1, js, t + 1);
        }
    } else {
        for (int t = 0; t < T_; ++t) {
            if (w == 0)               waitwave(flags, 1, t + 1, lane); // Q slot t done
            else if (w == 1 && t > 0) waitwave(flags, 2, t,     lane); // h2 slot t done
            __syncthreads();
            uint4 qp[4];
            if (kh == 0) {                      // Q loads complete under the GEMM
                const uint4* Qr = (const uint4*)(Qhist + (size_t)t * (4 * BH));
                #pragma unroll
                for (int r = 0; r < 4; ++r)
                    qp[r] = Qr[(size_t)(m0 + lq * 4 + r) * H_ + js * 16 + lm];
            }
            f32x4 acc[4];
            #pragma unroll
            for (int g = 0; g < 4; ++g) acc[g] = (f32x4){0.f, 0.f, 0.f, 0.f};
            gemm_half(h2hist + (size_t)t * BH, ws, lm, lq, m0, kh, acc);
            if (kh == 1) {
                #pragma unroll
                for (int g = 0; g < 4; ++g) pacc[pidx][g] = acc[g];
            }
            __syncthreads();
            if (kh == 0) {
                #pragma unroll
                for (int g = 0; g < 4; ++g) acc[g] += pacc[pidx][g];
                #pragma unroll
                for (int r = 0; r < 4; ++r) {
                    union { uint32_t u; float f; } x0, x1, x2, x3;
                    x0.u = qp[r].x; x1.u = qp[r].y; x2.u = qp[r].z; x3.u = qp[r].w;
                    acc[0][r] += x0.f; acc[1][r] += x1.f;
                    acc[2][r] += x2.f; acc[3][r] += x3.f;
                }
                #pragma unroll
                for (int r = 0; r < 4; ++r) {
                    if (t < q[r]) lstm_elem(acc, r, c_reg, h_reg, hb_reg);
                    hstage[m0 + lq * 4 + r][lm] = hb_reg[r];
                    if (q[r] == t + 1) {        // sample froze: publish fp32 h2 row
                        int b = m0 + lq * 4 + r, j = js * 16 + lm;
                        astoref(&h2f[(size_t)b * H_ + j], h_reg[r]);  // pre-drain => covered by flag2
                        __builtin_nontemporal_store(h_reg[r], &out[H2OFF + b * H_ + j]);
                        __builtin_nontemporal_store(c_reg[r], &out[C2OFF + b * H_ + j]);
                    }
                }
            }
            __syncthreads();
            if (threadIdx.x < 256)
                store_h_tile(h2hist + (size_t)(t + 1) * BH, js, &hstage[0][0]);
            __syncthreads();                    // drain (covers h2f stores too)
            if (threadIdx.x == 0) setflag(flags, 2, js, t + 1);  // ALL t (writers need 32)
        }
    }
}

// ---------------- launch ----------------
extern "C" void kernel_launch(void* const* d_in, const int* in_sizes, int n_in,
                              void* d_out, int out_size, void* d_ws, size_t ws_size,
                              hipStream_t stream) {
    const int*   questions = (const int*)d_in[0];
    const int*   qlen      = (const int*)d_in[1];
    const float* embed     = (const float*)d_in[2];
    const float* W_ih1     = (const float*)d_in[3];
    const float* W_hh1     = (const float*)d_in[4];
    const float* b_ih1     = (const float*)d_in[5];
    const float* b_hh1     = (const float*)d_in[6];
    const float* W_ih2     = (const float*)d_in[7];
    const float* W_hh2     = (const float*)d_in[8];
    const float* b_ih2     = (const float*)d_in[9];
    const float* b_hh2     = (const float*)d_in[10];
    float* out = (float*)d_out;

    char* w = (char*)d_ws;
    float*    xg     = (float*)(w + 0);                 // 33,554,432
    ushort_t* Wih1p  = (ushort_t*)(w + 33554432);       //  2,621,440
    ushort_t* Xp     = (ushort_t*)(w + 36175872);       //  1,310,720
    ushort_t* h1hist = (ushort_t*)(w + 37486592);       // 33*131,072 = 4,325,376
    ushort_t* h2hist = (ushort_t*)(w + 41811968);       // 33*131,072 = 4,325,376
    float*    Qhist  = (float*)(w + 46137344);          // 32*1,048,576 = 33,554,432
    float*    h2f    = (float*)(w + 80216064);          //    262,144 (writer source)
    int*      flags  = (int*)(w + 80740352);            // 12,288 -> end 80,752,640

    // all zero-init folded into prep_inputs -> zero memset dispatches
    prep_inputs<<<3395, 256, 0, stream>>>(questions, embed, Xp, W_ih1, Wih1p,
                                          h1hist, h2hist, flags);
    xgemm<<<dim3(32, 64), 256, 0, stream>>>(Xp, Wih1p, b_ih1, b_hh1, xg);

    lstm_persist<<<NBLK, 512, 0, stream>>>(W_hh1, W_ih2, W_hh2, b_ih2, b_hh2,
                                           xg, qlen,
                                           h1hist, h2hist, Qhist,
                                           h2f, out, flags);
}